// Round 2
// baseline (59.399 us; speedup 1.0000x reference)
//
#include <hip/hip_runtime.h>

#define EPS 1e-8f

// Shapes fixed per reference: x [B=8, N=8192, D=512] fp32, scalar fp32 out.
#define B_DIM 8
#define N_DIM 8192
#define D_DIM 512

// K1: grid = B * chunksPerBatch blocks, 256 threads (4 waves).
// Each wave processes rowsPerWave consecutive rows; lane l owns d-slice [8l, 8l+8).
// Block writes one 512-float partial sum vector (sum of normalized rows).
__global__ __launch_bounds__(256) void k1_partial(const float* __restrict__ x,
                                                  float* __restrict__ partial,
                                                  int rowsPerChunk,
                                                  int chunksPerBatch) {
    const int blk   = blockIdx.x;
    const int b     = blk / chunksPerBatch;
    const int chunk = blk % chunksPerBatch;
    const int wave  = threadIdx.x >> 6;   // 0..3
    const int lane  = threadIdx.x & 63;
    const int rowsPerWave = rowsPerChunk >> 2;

    const long long rowStart = (long long)b * N_DIM
                             + (long long)chunk * rowsPerChunk
                             + (long long)wave * rowsPerWave;

    float acc[8];
    #pragma unroll
    for (int k = 0; k < 8; ++k) acc[k] = 0.0f;

    const float* base = x + rowStart * D_DIM + lane * 8;

    for (int r = 0; r < rowsPerWave; ++r) {
        const float4 v0 = *(const float4*)(base);
        const float4 v1 = *(const float4*)(base + 4);
        base += D_DIM;

        float ss = v0.x*v0.x + v0.y*v0.y + v0.z*v0.z + v0.w*v0.w
                 + v1.x*v1.x + v1.y*v1.y + v1.z*v1.z + v1.w*v1.w;
        // full 64-lane butterfly reduce
        #pragma unroll
        for (int off = 1; off < 64; off <<= 1)
            ss += __shfl_xor(ss, off);

        const float inv = 1.0f / fmaxf(sqrtf(ss), EPS);

        acc[0] += v0.x * inv; acc[1] += v0.y * inv;
        acc[2] += v0.z * inv; acc[3] += v0.w * inv;
        acc[4] += v1.x * inv; acc[5] += v1.y * inv;
        acc[6] += v1.z * inv; acc[7] += v1.w * inv;
    }

    // combine the 4 waves' partials deterministically via LDS
    __shared__ float lds[4][D_DIM];
    float* dst = &lds[wave][lane * 8];
    #pragma unroll
    for (int k = 0; k < 8; ++k) dst[k] = acc[k];
    __syncthreads();

    for (int d = threadIdx.x; d < D_DIM; d += 256) {
        float s = lds[0][d] + lds[1][d] + lds[2][d] + lds[3][d];
        partial[(long long)blk * D_DIM + d] = s;
    }
}

// K2: one block per batch, 512 threads (thread = one d). Sum partials over
// chunks, square, block-reduce to per-batch ||s||^2.
__global__ __launch_bounds__(512) void k2_batch(const float* __restrict__ partial,
                                                float* __restrict__ perBatch,
                                                int chunksPerBatch) {
    const int b = blockIdx.x;
    const int d = threadIdx.x;

    float s = 0.0f;
    const float* p = partial + (long long)b * chunksPerBatch * D_DIM + d;
    for (int c = 0; c < chunksPerBatch; ++c) s += p[(long long)c * D_DIM];

    float v = s * s;
    #pragma unroll
    for (int off = 1; off < 64; off <<= 1)
        v += __shfl_xor(v, off);

    __shared__ float lds[8];
    if ((threadIdx.x & 63) == 0) lds[threadIdx.x >> 6] = v;
    __syncthreads();
    if (threadIdx.x == 0) {
        float t = 0.0f;
        #pragma unroll
        for (int w = 0; w < 8; ++w) t += lds[w];
        perBatch[b] = t;
    }
}

// K3: final scalar.
__global__ void k3_final(const float* __restrict__ perBatch,
                         float* __restrict__ out) {
    if (threadIdx.x == 0 && blockIdx.x == 0) {
        float t = 0.0f;
        #pragma unroll
        for (int b = 0; b < B_DIM; ++b) t += perBatch[b];
        out[0] = t / ((float)N_DIM * (float)N_DIM * (float)B_DIM);
    }
}

extern "C" void kernel_launch(void* const* d_in, const int* in_sizes, int n_in,
                              void* d_out, int out_size, void* d_ws, size_t ws_size,
                              hipStream_t stream) {
    const float* x = (const float*)d_in[0];
    float* out = (float*)d_out;

    // Size the chunk count to the workspace: need B*chunks*512 floats for
    // partials + B floats for per-batch results.
    int chunks = 128;
    while (chunks > 1 &&
           ((size_t)B_DIM * chunks * D_DIM + B_DIM) * sizeof(float) > ws_size) {
        chunks >>= 1;
    }
    const int rowsPerChunk = N_DIM / chunks;

    float* partial  = (float*)d_ws;
    float* perBatch = partial + (size_t)B_DIM * chunks * D_DIM;

    k1_partial<<<dim3(B_DIM * chunks), dim3(256), 0, stream>>>(x, partial,
                                                               rowsPerChunk, chunks);
    k2_batch<<<dim3(B_DIM), dim3(512), 0, stream>>>(partial, perBatch, chunks);
    k3_final<<<dim3(1), dim3(64), 0, stream>>>(perBatch, out);
}

// Round 3
// 37.826 us; speedup vs baseline: 1.5703x; 1.5703x over previous
//
#include <hip/hip_runtime.h>

#define EPS 1e-8f

// Shapes fixed per reference: x [B=8, N=8192, D=512] fp32, scalar fp32 out.
#define B_DIM 8
#define N_DIM 8192
#define D_DIM 512
#define CHUNKS 128   // K1 grid = B*CHUNKS = 1024 blocks (4/CU)

// K1: 256 threads (4 waves). Each wave processes rowsPerWave consecutive rows,
// 2 rows per iteration for ILP; lane l owns d-slice [8l, 8l+8).
// Block writes one 512-float partial sum vector (sum of normalized rows).
__global__ __launch_bounds__(256) void k1_partial(const float* __restrict__ x,
                                                  float* __restrict__ partial) {
    const int blk   = blockIdx.x;
    const int b     = blk >> 7;          // / CHUNKS
    const int chunk = blk & (CHUNKS - 1);
    const int wave  = threadIdx.x >> 6;  // 0..3
    const int lane  = threadIdx.x & 63;
    const int rowsPerChunk = N_DIM / CHUNKS;      // 64
    const int rowsPerWave  = rowsPerChunk >> 2;   // 16 (even)

    const long long rowStart = (long long)b * N_DIM
                             + (long long)chunk * rowsPerChunk
                             + (long long)wave * rowsPerWave;

    float acc[8];
    #pragma unroll
    for (int k = 0; k < 8; ++k) acc[k] = 0.0f;

    const float* base = x + rowStart * D_DIM + lane * 8;

    for (int r = 0; r < rowsPerWave; r += 2) {
        const float4 a0 = *(const float4*)(base);
        const float4 a1 = *(const float4*)(base + 4);
        const float4 b0 = *(const float4*)(base + D_DIM);
        const float4 b1 = *(const float4*)(base + D_DIM + 4);
        base += 2 * D_DIM;

        float ssA = a0.x*a0.x + a0.y*a0.y + a0.z*a0.z + a0.w*a0.w
                  + a1.x*a1.x + a1.y*a1.y + a1.z*a1.z + a1.w*a1.w;
        float ssB = b0.x*b0.x + b0.y*b0.y + b0.z*b0.z + b0.w*b0.w
                  + b1.x*b1.x + b1.y*b1.y + b1.z*b1.z + b1.w*b1.w;

        // two interleaved 64-lane butterflies (independent chains)
        #pragma unroll
        for (int off = 1; off < 64; off <<= 1) {
            ssA += __shfl_xor(ssA, off);
            ssB += __shfl_xor(ssB, off);
        }

        const float invA = 1.0f / fmaxf(sqrtf(ssA), EPS);
        const float invB = 1.0f / fmaxf(sqrtf(ssB), EPS);

        acc[0] += a0.x * invA + b0.x * invB;
        acc[1] += a0.y * invA + b0.y * invB;
        acc[2] += a0.z * invA + b0.z * invB;
        acc[3] += a0.w * invA + b0.w * invB;
        acc[4] += a1.x * invA + b1.x * invB;
        acc[5] += a1.y * invA + b1.y * invB;
        acc[6] += a1.z * invA + b1.z * invB;
        acc[7] += a1.w * invA + b1.w * invB;
    }

    // combine the 4 waves' partials deterministically via LDS
    __shared__ float lds[4][D_DIM];
    float* dst = &lds[wave][lane * 8];
    #pragma unroll
    for (int k = 0; k < 8; ++k) dst[k] = acc[k];
    __syncthreads();

    for (int d = threadIdx.x; d < D_DIM; d += 256) {
        float s = lds[0][d] + lds[1][d] + lds[2][d] + lds[3][d];
        partial[(long long)blk * D_DIM + d] = s;
    }
}

// K2: 64 blocks = 8 batches x 8 d-groups (64 d's each), 256 threads.
// Wave q sums chunks c === q (mod 4) for its 64 d's; LDS-combine the 4 waves,
// square, 64-lane reduce -> one partial ssq per block.
__global__ __launch_bounds__(256) void k2_batch(const float* __restrict__ partial,
                                                float* __restrict__ ssqPartial) {
    const int b  = blockIdx.x >> 3;
    const int g  = blockIdx.x & 7;
    const int dl = threadIdx.x & 63;
    const int q  = threadIdx.x >> 6;
    const int d  = g * 64 + dl;

    float s = 0.0f;
    const float* p = partial + (long long)b * CHUNKS * D_DIM + d;
    for (int c = q; c < CHUNKS; c += 4) s += p[(long long)c * D_DIM];

    __shared__ float lds[4][64];
    lds[q][dl] = s;
    __syncthreads();

    if (q == 0) {
        const float tot = lds[0][dl] + lds[1][dl] + lds[2][dl] + lds[3][dl];
        float v = tot * tot;
        #pragma unroll
        for (int off = 1; off < 64; off <<= 1) v += __shfl_xor(v, off);
        if (dl == 0) ssqPartial[blockIdx.x] = v;
    }
}

// K3: 64 partial ssq values -> scalar.
__global__ void k3_final(const float* __restrict__ ssqPartial,
                         float* __restrict__ out) {
    float v = ssqPartial[threadIdx.x & 63];
    #pragma unroll
    for (int off = 1; off < 64; off <<= 1) v += __shfl_xor(v, off);
    if (threadIdx.x == 0)
        out[0] = v / ((float)N_DIM * (float)N_DIM * (float)B_DIM);
}

extern "C" void kernel_launch(void* const* d_in, const int* in_sizes, int n_in,
                              void* d_out, int out_size, void* d_ws, size_t ws_size,
                              hipStream_t stream) {
    const float* x = (const float*)d_in[0];
    float* out = (float*)d_out;

    float* partial    = (float*)d_ws;                               // B*CHUNKS*512 floats = 2 MB
    float* ssqPartial = partial + (size_t)B_DIM * CHUNKS * D_DIM;   // 64 floats

    k1_partial<<<dim3(B_DIM * CHUNKS), dim3(256), 0, stream>>>(x, partial);
    k2_batch<<<dim3(B_DIM * 8), dim3(256), 0, stream>>>(partial, ssqPartial);
    k3_final<<<dim3(1), dim3(64), 0, stream>>>(ssqPartial, out);
}